// Round 11
// baseline (216.813 us; speedup 1.0000x reference)
//
#include <hip/hip_runtime.h>
#include <cfloat>
#include <cmath>

#define HH   2048
#define ISZ  4096
#define WN   10
#define ND   6
#define EPSF 1e-9f

// ---- workspace layout (float offsets) ----
#define O_WROW   0          // 7*2048
#define O_GETW   14336      // 5*16
#define O_POPC   14464      // 6*4
#define O_AVAIL  14496      // 6
#define O_SCAL   14528      // [0:6]pp [6:12]gate1 [12:18]perp [24:30]sQi [30:36]sQh
#define O_IPTR   14592      // 6*16
#define O_DFIN   14720      // 6*2048
#define O_CNEW   27008      // 6*2048
#define O_CFIN   39296      // 6*4*2048
#define O_SPTR   88448      // 6*2048
#define O_NEWINP 100736     // 6*4096 (V rows 0..5)
#define O_G      125312     // 5*4096 (V rows 6..9 = g[0..3]; MUST follow O_NEWINP)
#define O_HVEC   145792     // 6*4096
#define O_IVEC   170368     // 6*4096
#define O_RPART  317824     // 32*7*4096 rowsum partials (end 1235328)
#define O_PZ     1235328    // 4*6*4096 partials for Z (kin1 ks0/1, kin2 ks0/1)
#define O_PYFF   1333632    // 2*6*4096
#define O_PYH    1382784    // 2*6*4096
#define O_PYI    1431936    // 2*6*4096

__device__ __forceinline__ float blockReduceSum(float v, float* sm){
  int ln = threadIdx.x & 63, w = threadIdx.x >> 6;
  #pragma unroll
  for (int o=32;o>0;o>>=1) v += __shfl_down(v,o);
  if (ln==0) sm[w]=v;
  __syncthreads();
  if (threadIdx.x==0){
    float r=0.f; int nw=(int)(blockDim.x>>6);
    for (int i=0;i<nw;i++) r+=sm[i];
    sm[16]=r;
  }
  __syncthreads();
  float r = sm[16];
  __syncthreads();
  return r;
}

template<int N>
__device__ __forceinline__ void bRedSumN(float* v, float* sm){
  int ln=threadIdx.x&63, w=threadIdx.x>>6;
  #pragma unroll
  for (int o=32;o>0;o>>=1){
    #pragma unroll
    for (int i=0;i<N;i++) v[i]+=__shfl_down(v[i],o);
  }
  if (ln==0){ for (int i=0;i<N;i++) sm[w*N+i]=v[i]; }
  __syncthreads();
  if (threadIdx.x==0){
    for (int i=0;i<N;i++){ float r=0.f; for (int q=0;q<16;q++) r+=sm[q*N+i]; sm[16*N+i]=r; }
  }
  __syncthreads();
  for (int i=0;i<N;i++) v[i]=sm[16*N+i];
  __syncthreads();
}

template<int N>
__device__ __forceinline__ void bRedMaxN(float* v, float* sm){
  int ln=threadIdx.x&63, w=threadIdx.x>>6;
  #pragma unroll
  for (int o=32;o>0;o>>=1){
    #pragma unroll
    for (int i=0;i<N;i++) v[i]=fmaxf(v[i],__shfl_down(v[i],o));
  }
  if (ln==0){ for (int i=0;i<N;i++) sm[w*N+i]=v[i]; }
  __syncthreads();
  if (threadIdx.x==0){
    for (int i=0;i<N;i++){ float r=-FLT_MAX; for (int q=0;q<16;q++) r=fmaxf(r,sm[q*N+i]); sm[16*N+i]=r; }
  }
  __syncthreads();
  for (int i=0;i<N;i++) v[i]=sm[16*N+i];
  __syncthreads();
}

// ---------------------------------------------------------------------------
// K1: pointer algebra (data-independent). 6 blocks x 1024 threads.
// ---------------------------------------------------------------------------
__global__ __launch_bounds__(1024) void k_ptr_prep(
    const float* __restrict__ sp0g, const float* __restrict__ ip0g,
    float* __restrict__ ws)
{
  __shared__ float sp[HH], q[HH], D[HH];
  __shared__ float c[4][HH];
  __shared__ float red[17];
  const int d   = blockIdx.x;
  const int tid = threadIdx.x;

  float* Wrow = ws + O_WROW;
  float* getW = ws + O_GETW;
  float* popc = ws + O_POPC;
  float* Dfin = ws + O_DFIN;
  float* cnew = ws + O_CNEW;
  float* cfin = ws + O_CFIN;
  float* sptr = ws + O_SPTR;
  float* iptr = ws + O_IPTR;
  float* avail= ws + O_AVAIL;

  if (d==0 && tid==0){
    float ip[WN+1], nip[WN+1];
    for (int k=0;k<=WN;k++) ip[k]=ip0g[k];
    for (int k=0;k<=WN;k++) iptr[k]=ip[k];
    avail[0] = 1.f - ip[WN];
    for (int t=0;t<5;t++){
      for (int k=0;k<WN;k++) getW[t*16+k]=ip[k];
      nip[0]=0.f;
      for (int k=1;k<=WN;k++) nip[k]=ip[k-1];
      nip[WN] += ip[WN];
      for (int k=0;k<=WN;k++) ip[k]=nip[k];
      for (int k=0;k<=WN;k++) iptr[(t+1)*16+k]=ip[k];
      avail[t+1] = 1.f - ip[WN];
    }
  }

  #pragma unroll
  for (int jj=0;jj<2;jj++){ int j=tid+jj*1024; sp[j]=sp0g[j]; D[j]=1.f; }
  __syncthreads();

  if (d==0){
    #pragma unroll
    for (int jj=0;jj<2;jj++){ int j=tid+jj*1024; q[j]=(j<HH-1)? sp[j+1]:0.f; }
    float ls=0.f;
    #pragma unroll
    for (int jj=0;jj<2;jj++) ls += q[tid+jj*1024];
    float s = blockReduceSum(ls, red);
    float sc = (s>0.f)? 1.f/s : 1.f;
    #pragma unroll
    for (int jj=0;jj<2;jj++){
      int j=tid+jj*1024;
      float qq=q[j];
      Wrow[j] = qq*sc;
      D[j] = 1.f - qq;
      sp[j] = qq + ((j==0)? sp[0] : 0.f);
    }
    __syncthreads();
    #pragma unroll
    for (int jj=0;jj<2;jj++){ int j=tid+jj*1024; q[j]=(j<HH-1)? sp[j+1]:0.f; }
    ls=0.f;
    #pragma unroll
    for (int jj=0;jj<2;jj++) ls += q[tid+jj*1024];
    s = blockReduceSum(ls, red);
    sc = (s>0.f)? 1.f/s : 1.f;
    #pragma unroll
    for (int jj=0;jj<2;jj++){
      int j=tid+jj*1024;
      float qq=q[j];
      Wrow[HH+j] = qq*sc*D[j];
      D[j] *= (1.f-qq);
      sp[j] = qq + ((j==0)? sp[0] : 0.f);
    }
    __syncthreads();
    #pragma unroll
    for (int jj=0;jj<2;jj++){
      int j=tid+jj*1024;
      float p=sp[j];
      Dfin[j] = D[j]*(1.f-p);
      cnew[j] = p;
      sptr[j] = (j==0)? 0.f : sp[j-1];
    }
  } else {
    const int nterms = d-1;
    for (int t=0;t<nterms;t++){
      #pragma unroll
      for (int jj=0;jj<2;jj++){
        int j=tid+jj*1024;
        float p=sp[j], f=1.f-p;
        D[j]*=f;
        for (int u=0;u<t;u++) c[u][j]*=f;
        c[t][j]=p;
      }
      __syncthreads();
      float sv[2];
      #pragma unroll
      for (int jj=0;jj<2;jj++){ int j=tid+jj*1024; sv[jj]=(j==0)?0.f:sp[j-1]; }
      __syncthreads();
      #pragma unroll
      for (int jj=0;jj<2;jj++){ int j=tid+jj*1024; sp[j]=sv[jj]; }
      __syncthreads();
    }
    #pragma unroll
    for (int jj=0;jj<2;jj++){ int j=tid+jj*1024; q[j]=(j<HH-1)? sp[j+1]:0.f; }
    float ls=0.f;
    #pragma unroll
    for (int jj=0;jj<2;jj++) ls += q[tid+jj*1024];
    float s = blockReduceSum(ls, red);
    float sc = (s>0.f)? 1.f/s : 1.f;
    for (int t=0;t<nterms;t++){
      float pc=0.f;
      #pragma unroll
      for (int jj=0;jj<2;jj++){ int j=tid+jj*1024; pc += q[j]*sc*c[t][j]; }
      pc = blockReduceSum(pc, red);
      if (tid==0) popc[d*4+t]=pc;
    }
    #pragma unroll
    for (int jj=0;jj<2;jj++){
      int j=tid+jj*1024;
      float qq=q[j];
      Wrow[(1+d)*HH+j] = qq*sc*D[j];
      float f = 1.f-qq;
      D[j] *= f;
      for (int t=0;t<nterms;t++) c[t][j] *= f;
      sp[j] = qq + ((j==0)? sp[0] : 0.f);
    }
    __syncthreads();
    #pragma unroll
    for (int jj=0;jj<2;jj++){
      int j=tid+jj*1024;
      float p=sp[j], f=1.f-p;
      Dfin[d*HH+j] = D[j]*f;
      for (int t=0;t<nterms;t++) cfin[(d*4+t)*HH+j] = c[t][j]*f;
      cnew[d*HH+j] = p;
      sptr[d*HH+j] = (j==0)? 0.f : sp[j-1];
    }
  }
}

// ---------------------------------------------------------------------------
// K2: rowsum partials, atomic-free: Rp[y][k][col]
// ---------------------------------------------------------------------------
__global__ __launch_bounds__(256) void k_rowsum(
    const float* __restrict__ stk, const float* __restrict__ wrow,
    float* __restrict__ Rp)
{
  __shared__ float wsh[7][64];
  const int col = blockIdx.x*256 + threadIdx.x;
  const int by  = blockIdx.y;
  const int r0  = by*64;
  for (int idx=threadIdx.x; idx<7*64; idx+=256){
    int k=idx>>6, r=idx&63;
    wsh[k][r]=wrow[k*HH + r0 + r];
  }
  __syncthreads();
  float a0=0,a1=0,a2=0,a3=0,a4=0,a5=0,a6=0;
  const float* sp = stk + (size_t)r0*ISZ + col;
  #pragma unroll 4
  for (int r=0;r<64;r++){
    float v = sp[(size_t)r*ISZ];
    a0+=wsh[0][r]*v; a1+=wsh[1][r]*v; a2+=wsh[2][r]*v; a3+=wsh[3][r]*v;
    a4+=wsh[4][r]*v; a5+=wsh[5][r]*v; a6+=wsh[6][r]*v;
  }
  Rp[(size_t)(by*7+0)*ISZ+col]=a0; Rp[(size_t)(by*7+1)*ISZ+col]=a1;
  Rp[(size_t)(by*7+2)*ISZ+col]=a2; Rp[(size_t)(by*7+3)*ISZ+col]=a3;
  Rp[(size_t)(by*7+4)*ISZ+col]=a4; Rp[(size_t)(by*7+5)*ISZ+col]=a5;
  Rp[(size_t)(by*7+6)*ISZ+col]=a6;
}

// ---------------------------------------------------------------------------
// K3: fused g-vectors + R reduction + Ivec/Hvec assembly
// ---------------------------------------------------------------------------
__global__ __launch_bounds__(128) void k_hv(
    const float* __restrict__ input, float* __restrict__ ws)
{
  __shared__ float gwS[80], pcS[24];
  const int tid=threadIdx.x;
  const int cx = blockIdx.x*128 + tid;
  if (tid<80) gwS[tid]=ws[O_GETW+tid];
  if (tid<24) pcS[tid]=ws[O_POPC+tid];
  __syncthreads();
  float inp[WN];
  #pragma unroll
  for (int k=0;k<WN;k++) inp[k]=input[k*ISZ+cx];
  float g[5];
  #pragma unroll
  for (int t=0;t<5;t++){
    float a=0.f;
    #pragma unroll
    for (int k=0;k<WN;k++) a += gwS[t*16+k]*inp[k];
    g[t]=a;
    ws[O_G + t*ISZ + cx]=a;
  }
  float R[7];
  #pragma unroll
  for (int k=0;k<7;k++){
    float a=0.f;
    for (int y=0;y<32;y++) a += ws[O_RPART + (size_t)(y*7+k)*ISZ + cx];
    R[k]=a;
  }
  ws[O_IVEC + cx]=R[0];
  ws[O_HVEC + cx]=R[1];
  #pragma unroll
  for (int d=1;d<ND;d++){
    ws[O_IVEC + d*ISZ + cx] = g[d-1];
    float h = R[1+d];
    for (int t=0;t<=d-2;t++) h += pcS[d*4+t]*g[t];
    ws[O_HVEC + d*ISZ + cx] = h;
  }
}

// ---------------------------------------------------------------------------
// Matvec: X k-slice (6x2048 = 48 KB) staged in LDS once per block; weight
// stream fully pre-issued (16 float4 loads/wave up-front -> 16 KB in flight,
// no VMEM-pipe traffic for X). 8 waves x 2 rows = 16 rows/block, k-split 2.
// VMEM bytes/CU drop 3MB -> ~1MB vs R9 (X was 3x the weight traffic through
// the same per-CU TA pipe; L3-resident replays at equal speed proved the
// pipe, not HBM, was the limit).
// ---------------------------------------------------------------------------
#define KCH 2048

__device__ __forceinline__ void mv_lds(
    const float* __restrict__ W, int ldw, int wcol0,
    const float* __restrict__ Xg, const float* __restrict__ bias,
    float* __restrict__ Yp, int rb, int kbase, float* xls)
{
  // stage X[6][KCH] into LDS
  for (int idx=threadIdx.x; idx<6*KCH/4; idx+=512){
    int dd = idx>>9, j = idx&511;
    ((float4*)xls)[idx] = *(const float4*)(Xg + dd*ISZ + kbase + j*4);
  }
  __syncthreads();

  const int wv = threadIdx.x>>6, ln = threadIdx.x&63;
  const int row0 = rb*16 + wv*2;
  const float* wr0 = W + (size_t)row0*ldw + wcol0 + kbase + ln*4;
  const float* wr1 = wr0 + ldw;

  // pre-issue the entire weight stream for both rows (16 loads in flight)
  float4 w0[8], w1[8];
  #pragma unroll
  for (int i=0;i<8;i++){
    w0[i] = *(const float4*)(wr0 + i*256);
    w1[i] = *(const float4*)(wr1 + i*256);
  }

  float a0[6]={0,0,0,0,0,0}, a1[6]={0,0,0,0,0,0};
  #pragma unroll
  for (int i=0;i<8;i++){
    float4 x[6];
    #pragma unroll
    for (int dd=0;dd<6;dd++) x[dd] = *(const float4*)(xls + dd*KCH + i*256 + ln*4);
    #pragma unroll
    for (int dd=0;dd<6;dd++){
      a0[dd] += w0[i].x*x[dd].x + w0[i].y*x[dd].y + w0[i].z*x[dd].z + w0[i].w*x[dd].w;
      a1[dd] += w1[i].x*x[dd].x + w1[i].y*x[dd].y + w1[i].z*x[dd].z + w1[i].w*x[dd].w;
    }
  }

  #pragma unroll
  for (int dd=0;dd<6;dd++){
    float v0=a0[dd], v1=a1[dd];
    #pragma unroll
    for (int o=32;o>0;o>>=1){ v0+=__shfl_down(v0,o); v1+=__shfl_down(v1,o); }
    if (ln==0){
      Yp[dd*ISZ+row0]   = v0 + (bias? bias[row0]   : 0.f);
      Yp[dd*ISZ+row0+1] = v1 + (bias? bias[row0+1] : 0.f);
    }
  }
}

// task0: kin1(IVEC)->PZ[ks] | task1: ff(HVEC)->PYFF[ks] | task2: kin2(HVEC)->PZ[2+ks]
__global__ __launch_bounds__(512) void k_matvecA(
    const float* __restrict__ ff_w, const float* __restrict__ ff_b,
    const float* __restrict__ kin_w, const float* __restrict__ kin_b,
    float* __restrict__ ws)
{
  __shared__ float xls[6*KCH];
  const int task = blockIdx.x >> 9;
  const int rem  = blockIdx.x & 511;
  const int ks   = rem >> 8;
  const int rb   = rem & 255;
  const int kb   = ks*KCH;
  if (task==0)
    mv_lds(kin_w, 2*ISZ, 0,   ws+O_IVEC, (ks==0)?kin_b:nullptr,
           ws+O_PZ + ks*6*ISZ, rb, kb, xls);
  else if (task==1)
    mv_lds(ff_w,  ISZ,   0,   ws+O_HVEC, (ks==0)?ff_b:nullptr,
           ws+O_PYFF + ks*6*ISZ, rb, kb, xls);
  else
    mv_lds(kin_w, 2*ISZ, ISZ, ws+O_HVEC, nullptr,
           ws+O_PZ + (2+ks)*6*ISZ, rb, kb, xls);
}

// task0: kouth(NEWINP)->PYH[ks] | task1: kouti(NEWINP)->PYI[ks]
__global__ __launch_bounds__(512) void k_matvecB(
    const float* __restrict__ kouth_w, const float* __restrict__ kouth_b,
    const float* __restrict__ kouti_w, const float* __restrict__ kouti_b,
    float* __restrict__ ws)
{
  __shared__ float xls[6*KCH];
  const int task = blockIdx.x >> 9;
  const int rem  = blockIdx.x & 511;
  const int ks   = rem >> 8;
  const int rb   = rem & 255;
  const int kb   = ks*KCH;
  if (task==0)
    mv_lds(kouth_w, ISZ, 0, ws+O_NEWINP, (ks==0)?kouth_b:nullptr,
           ws+O_PYH + ks*6*ISZ, rb, kb, xls);
  else
    mv_lds(kouti_w, ISZ, 0, ws+O_NEWINP, (ks==0)?kouti_b:nullptr,
           ws+O_PYI + ks*6*ISZ, rb, kb, xls);
}

// ---------------------------------------------------------------------------
// S1: perp_pred KLD, softmax(z)->new_inp, gate   (6 blocks)
// ---------------------------------------------------------------------------
__global__ __launch_bounds__(1024) void k_s1(
    const float* __restrict__ gate_w, const float* __restrict__ gate_b,
    float* __restrict__ ws)
{
  __shared__ float sm[96];
  const int d=blockIdx.x, tid=threadIdx.x;
  const float* iv = ws+O_IVEC+ d*ISZ;
  const float* hv = ws+O_HVEC+ d*ISZ;

  float yv[4], zv[4], ivv[4], hvv[4];
  #pragma unroll
  for (int i=0;i<4;i++){
    int cx=tid+i*1024;
    float y=0.f, z=0.f;
    #pragma unroll
    for (int s=0;s<2;s++) y += ws[O_PYFF + (s*6+d)*ISZ + cx];
    #pragma unroll
    for (int s=0;s<4;s++) z += ws[O_PZ   + (s*6+d)*ISZ + cx];
    yv[i]=y; zv[i]=z; ivv[i]=iv[cx]; hvv[i]=hv[cx];
  }
  float mx[2]={-FLT_MAX,-FLT_MAX};
  #pragma unroll
  for (int i=0;i<4;i++){ mx[0]=fmaxf(mx[0],yv[i]); mx[1]=fmaxf(mx[1],zv[i]); }
  bRedMaxN<2>(mx,sm);

  float s5[5]={0,0,0,0,0};
  #pragma unroll
  for (int i=0;i<4;i++){
    s5[0]+=expf(yv[i]-mx[0]); s5[1]+=expf(zv[i]-mx[1]);
    s5[2]+=yv[i]; s5[3]+=ivv[i]; s5[4]+=hvv[i];
  }
  bRedSumN<5>(s5,sm);
  const float lse = mx[0]+logf(s5[0]);
  const float sP  = s5[2] - (float)ISZ*lse + (float)ISZ*EPSF;
  const float sQ  = s5[3] + (float)ISZ*EPSF;
  const float inv2= 1.f/s5[1];

  float kk[1]={0.f};
  #pragma unroll
  for (int i=0;i<4;i++){
    int cx=tid+i*1024;
    ws[O_NEWINP + d*ISZ + cx] = expf(zv[i]-mx[1])*inv2;
    float ph=((yv[i]-lse)+EPSF)/sP;
    float qh=(ivv[i]+EPSF)/sQ;
    kk[0]+=ph*(logf(ph)-logf(qh));
  }
  bRedSumN<1>(kk,sm);

  if (tid==0){
    float pp=kk[0];
    float a0=gate_w[0]*pp+gate_b[0];
    float a1=gate_w[1]*pp+gate_b[1];
    float mg=fmaxf(a0,a1);
    float e0=expf(a0-mg), e1=expf(a1-mg);
    float g1=e1/(e0+e1);
    if (s5[4]==0.f) g1=0.f;
    else if (s5[3]==0.f) g1=1.f;
    ws[O_SCAL+d]=pp; ws[O_SCAL+6+d]=g1;
    ws[O_SCAL+24+d]=sQ;
    ws[O_SCAL+30+d]=s5[4]+(float)ISZ*EPSF;
  }
}

// ---------------------------------------------------------------------------
// S2: both output KLDs, batched  (6 blocks)
// ---------------------------------------------------------------------------
__global__ __launch_bounds__(1024) void k_s2(float* __restrict__ ws)
{
  __shared__ float sm[96];
  const int d=blockIdx.x, tid=threadIdx.x;
  const float* hv = ws+O_HVEC+ d*ISZ;
  const float* iv = ws+O_IVEC+ d*ISZ;

  float yhv[4], yiv[4], hvv[4], ivv[4];
  #pragma unroll
  for (int i=0;i<4;i++){
    int cx=tid+i*1024;
    float yh=0.f, yi=0.f;
    #pragma unroll
    for (int s=0;s<2;s++){
      yh += ws[O_PYH + (s*6+d)*ISZ + cx];
      yi += ws[O_PYI + (s*6+d)*ISZ + cx];
    }
    yhv[i]=yh; yiv[i]=yi; hvv[i]=hv[cx]; ivv[i]=iv[cx];
  }
  float mx[2]={-FLT_MAX,-FLT_MAX};
  #pragma unroll
  for (int i=0;i<4;i++){ mx[0]=fmaxf(mx[0],yhv[i]); mx[1]=fmaxf(mx[1],yiv[i]); }
  bRedMaxN<2>(mx,sm);
  float se[2]={0,0};
  #pragma unroll
  for (int i=0;i<4;i++){ se[0]+=expf(yhv[i]-mx[0]); se[1]+=expf(yiv[i]-mx[1]); }
  bRedSumN<2>(se,sm);
  const float invh=1.f/se[0], invi=1.f/se[1];
  const float spc = 1.f + (float)ISZ*EPSF;
  const float sqh = ws[O_SCAL+30+d], sqi = ws[O_SCAL+24+d];

  float kk[2]={0,0};
  #pragma unroll
  for (int i=0;i<4;i++){
    float ph=(expf(yhv[i]-mx[0])*invh+EPSF)/spc;
    float qh=(hvv[i]+EPSF)/sqh;
    kk[0]+=ph*(logf(ph)-logf(qh));
    float pi=(expf(yiv[i]-mx[1])*invi+EPSF)/spc;
    float qi=(ivv[i]+EPSF)/sqi;
    kk[1]+=pi*(logf(pi)-logf(qi));
  }
  bRedSumN<2>(kk,sm);
  if (tid==0) ws[O_SCAL+12+d] = ws[O_SCAL+d] + 0.5f*(kk[0]+kk[1]);
}

// ---------------------------------------------------------------------------
// FIN: w chain + resperp + new_sp + new_ip  (1 block)
// ---------------------------------------------------------------------------
__global__ __launch_bounds__(1024) void k_fin(float* __restrict__ ws,
                                              float* __restrict__ out)
{
  __shared__ float sm[32];
  __shared__ float wsh[ND];
  const int tid=threadIdx.x;
  if (tid==0){
    const float* g1=ws+O_SCAL+6; const float* pp=ws+O_SCAL+12; const float* av=ws+O_AVAIL;
    float wl[ND]; wl[0]=g1[0];
    for (int i=1;i<ND;i++) wl[i]=(1.f-wl[i-1])*g1[i]*av[i];
    float s=0.f; for (int i=0;i<ND;i++) s+=wl[i];
    float rp=0.f;
    for (int i=0;i<ND;i++){ float wn=wl[i]/s; wsh[i]=wn; rp+=wn*pp[i]; }
    out[0]=rp;
  }
  __syncthreads();
  float w[ND];
  #pragma unroll
  for (int dd=0;dd<ND;dd++) w[dd]=wsh[dd];
  const float* sptr=ws+O_SPTR;
  float snl[2], ms=0.f;
  #pragma unroll
  for (int jj=0;jj<2;jj++){
    int j=tid+jj*1024;
    float sn=0.f;
    #pragma unroll
    for (int dd=0;dd<ND;dd++) sn += w[dd]*sptr[dd*HH+j];
    snl[jj]=sn; ms+=sn;
  }
  float t[1]={ms};
  bRedSumN<1>(t,sm);
  float ssum=t[0];
  #pragma unroll
  for (int jj=0;jj<2;jj++){
    int j=tid+jj*1024;
    out[1 + (size_t)HH*ISZ + j] = (ssum>0.f)? snl[jj]/ssum : snl[jj];
  }
  if (tid==0){
    const float* iptr=ws+O_IPTR;
    float ipn[WN+1]; float is=0.f;
    for (int k=0;k<=WN;k++){
      float a=0.f;
      for (int dd=0;dd<ND;dd++) a += w[dd]*iptr[dd*16+k];
      ipn[k]=a; is+=a;
    }
    size_t base = 1 + (size_t)HH*ISZ + HH;
    for (int k=0;k<=WN;k++) out[base+k] = (is>0.f)? ipn[k]/is : ipn[k];
  }
}

// ---------------------------------------------------------------------------
// STACK_OUT: out = Mw[j]*stack + sum_v Ceff[j][v]*V[v]  (Mw/Ceff inline)
// ---------------------------------------------------------------------------
__global__ __launch_bounds__(256) void k_stack_out(
    const float* __restrict__ stk, const float* __restrict__ ws,
    float* __restrict__ out)
{
  __shared__ float Vt[10*1024];
  __shared__ float wsh[ND];
  __shared__ float mwS[8];
  __shared__ float ceS[8][10];
  const int tid=threadIdx.x;
  const int c0 = blockIdx.x*1024;
  const int j0 = blockIdx.y*8;

  if (tid==0){
    const float* g1=ws+O_SCAL+6; const float* av=ws+O_AVAIL;
    float wl[ND]; wl[0]=g1[0];
    for (int i=1;i<ND;i++) wl[i]=(1.f-wl[i-1])*g1[i]*av[i];
    float s=0.f; for (int i=0;i<ND;i++) s+=wl[i];
    for (int i=0;i<ND;i++) wsh[i]=wl[i]/s;
  }
  const float* V = ws+O_NEWINP;
  for (int idx=tid; idx<10*1024; idx+=256){
    int v=idx>>10, cc=idx&1023;
    Vt[idx] = V[v*ISZ + c0 + cc];
  }
  __syncthreads();
  if (tid<8){
    int j=j0+tid;
    float mw=0.f, ce[10]={0,0,0,0,0,0,0,0,0,0};
    for (int dd=0;dd<ND;dd++){
      float wd=wsh[dd];
      mw    += wd*ws[O_DFIN+dd*HH+j];
      ce[dd] = wd*ws[O_CNEW+dd*HH+j];
    }
    for (int t=0;t<4;t++){
      float a=0.f;
      for (int dd=t+2;dd<ND;dd++) a += wsh[dd]*ws[O_CFIN+(dd*4+t)*HH+j];
      ce[6+t]=a;
    }
    mwS[tid]=mw;
    for (int v=0;v<10;v++) ceS[tid][v]=ce[v];
  }
  __syncthreads();
  const int tx4 = tid*4;
  for (int r=0;r<8;r++){
    int j=j0+r;
    float mw = mwS[r];
    float4 sv = *(const float4*)(stk + (size_t)j*ISZ + c0 + tx4);
    float o0 = mw*sv.x, o1 = mw*sv.y, o2 = mw*sv.z, o3 = mw*sv.w;
    #pragma unroll
    for (int v=0;v<10;v++){
      const float* vr = Vt + v*1024 + tx4;
      float cv=ceS[r][v];
      o0 += cv*vr[0]; o1 += cv*vr[1]; o2 += cv*vr[2]; o3 += cv*vr[3];
    }
    float* op = out + 1 + (size_t)j*ISZ + c0 + tx4;
    op[0]=o0; op[1]=o1; op[2]=o2; op[3]=o3;
  }
}

extern "C" void kernel_launch(void* const* d_in, const int* in_sizes, int n_in,
                              void* d_out, int out_size, void* d_ws, size_t ws_size,
                              hipStream_t stream)
{
  (void)in_sizes; (void)n_in; (void)out_size; (void)ws_size;
  const float* input   = (const float*)d_in[0];
  const float* stack   = (const float*)d_in[1];
  const float* sp0     = (const float*)d_in[2];
  const float* ip0     = (const float*)d_in[3];
  const float* ff_w    = (const float*)d_in[4];
  const float* ff_b    = (const float*)d_in[5];
  const float* gate_w  = (const float*)d_in[6];
  const float* gate_b  = (const float*)d_in[7];
  const float* kin_w   = (const float*)d_in[8];
  const float* kin_b   = (const float*)d_in[9];
  const float* kouth_w = (const float*)d_in[10];
  const float* kouth_b = (const float*)d_in[11];
  const float* kouti_w = (const float*)d_in[12];
  const float* kouti_b = (const float*)d_in[13];
  float* out = (float*)d_out;
  float* ws  = (float*)d_ws;

  k_ptr_prep<<<ND,1024,0,stream>>>(sp0, ip0, ws);
  k_rowsum<<<dim3(16,32),256,0,stream>>>(stack, ws+O_WROW, ws+O_RPART);
  k_hv<<<32,128,0,stream>>>(input, ws);
  k_matvecA<<<1536,512,0,stream>>>(ff_w, ff_b, kin_w, kin_b, ws);
  k_s1<<<ND,1024,0,stream>>>(gate_w, gate_b, ws);
  k_matvecB<<<1024,512,0,stream>>>(kouth_w, kouth_b, kouti_w, kouti_b, ws);
  k_s2<<<ND,1024,0,stream>>>(ws);
  k_stack_out<<<dim3(4,256),256,0,stream>>>(stack, ws, out);
  k_fin<<<1,1024,0,stream>>>(ws, out);
}

// Round 12
// 186.332 us; speedup vs baseline: 1.1636x; 1.1636x over previous
//
#include <hip/hip_runtime.h>
#include <cfloat>
#include <cmath>

#define HH   2048
#define ISZ  4096
#define WN   10
#define ND   6
#define EPSF 1e-9f

// ---- workspace layout (float offsets), ~5 MB ----
#define O_WROW   0          // 7*2048
#define O_GETW   14336      // 5*16
#define O_POPC   14464      // 6*4
#define O_AVAIL  14496      // 6
#define O_SCAL   14528      // [0:6]pp [6:12]gate1 [12:18]perp [24:30]sQi [30:36]sQh
#define O_IPTR   14592      // 6*16
#define O_DFIN   14720      // 6*2048
#define O_CNEW   27008      // 6*2048
#define O_CFIN   39296      // 6*4*2048
#define O_SPTR   88448      // 6*2048
#define O_NEWINP 100736     // 6*4096 (V rows 0..5)
#define O_G      125312     // 5*4096 (V rows 6..9 = g[0..3]; MUST follow O_NEWINP)
#define O_HVEC   145792     // 6*4096
#define O_IVEC   170368     // 6*4096
#define O_YFF    194944     // 6*4096
#define O_Z1     219520     // 6*4096
#define O_Z2     244096     // 6*4096
#define O_YH     268672     // 6*4096
#define O_YI     293248     // 6*4096
#define O_RPART  317824     // 32*7*4096 rowsum partials

typedef float nf4 __attribute__((ext_vector_type(4)));
__device__ __forceinline__ nf4 ntload4(const float* p){
  return __builtin_nontemporal_load((const nf4*)p);
}

__device__ __forceinline__ float blockReduceSum(float v, float* sm){
  int ln = threadIdx.x & 63, w = threadIdx.x >> 6;
  #pragma unroll
  for (int o=32;o>0;o>>=1) v += __shfl_down(v,o);
  if (ln==0) sm[w]=v;
  __syncthreads();
  if (threadIdx.x==0){
    float r=0.f; int nw=(int)(blockDim.x>>6);
    for (int i=0;i<nw;i++) r+=sm[i];
    sm[16]=r;
  }
  __syncthreads();
  float r = sm[16];
  __syncthreads();
  return r;
}

template<int N>
__device__ __forceinline__ void bRedSumN(float* v, float* sm){
  int ln=threadIdx.x&63, w=threadIdx.x>>6;
  #pragma unroll
  for (int o=32;o>0;o>>=1){
    #pragma unroll
    for (int i=0;i<N;i++) v[i]+=__shfl_down(v[i],o);
  }
  if (ln==0){ for (int i=0;i<N;i++) sm[w*N+i]=v[i]; }
  __syncthreads();
  if (threadIdx.x==0){
    for (int i=0;i<N;i++){ float r=0.f; for (int q=0;q<16;q++) r+=sm[q*N+i]; sm[16*N+i]=r; }
  }
  __syncthreads();
  for (int i=0;i<N;i++) v[i]=sm[16*N+i];
  __syncthreads();
}

template<int N>
__device__ __forceinline__ void bRedMaxN(float* v, float* sm){
  int ln=threadIdx.x&63, w=threadIdx.x>>6;
  #pragma unroll
  for (int o=32;o>0;o>>=1){
    #pragma unroll
    for (int i=0;i<N;i++) v[i]=fmaxf(v[i],__shfl_down(v[i],o));
  }
  if (ln==0){ for (int i=0;i<N;i++) sm[w*N+i]=v[i]; }
  __syncthreads();
  if (threadIdx.x==0){
    for (int i=0;i<N;i++){ float r=-FLT_MAX; for (int q=0;q<16;q++) r=fmaxf(r,sm[q*N+i]); sm[16*N+i]=r; }
  }
  __syncthreads();
  for (int i=0;i<N;i++) v[i]=sm[16*N+i];
  __syncthreads();
}

// ---------------------------------------------------------------------------
// K1: pointer algebra (data-independent). 6 blocks x 1024 threads.
// ---------------------------------------------------------------------------
__global__ __launch_bounds__(1024) void k_ptr_prep(
    const float* __restrict__ sp0g, const float* __restrict__ ip0g,
    float* __restrict__ ws)
{
  __shared__ float sp[HH], q[HH], D[HH];
  __shared__ float c[4][HH];
  __shared__ float red[17];
  const int d   = blockIdx.x;
  const int tid = threadIdx.x;

  float* Wrow = ws + O_WROW;
  float* getW = ws + O_GETW;
  float* popc = ws + O_POPC;
  float* Dfin = ws + O_DFIN;
  float* cnew = ws + O_CNEW;
  float* cfin = ws + O_CFIN;
  float* sptr = ws + O_SPTR;
  float* iptr = ws + O_IPTR;
  float* avail= ws + O_AVAIL;

  if (d==0 && tid==0){
    float ip[WN+1], nip[WN+1];
    for (int k=0;k<=WN;k++) ip[k]=ip0g[k];
    for (int k=0;k<=WN;k++) iptr[k]=ip[k];
    avail[0] = 1.f - ip[WN];
    for (int t=0;t<5;t++){
      for (int k=0;k<WN;k++) getW[t*16+k]=ip[k];
      nip[0]=0.f;
      for (int k=1;k<=WN;k++) nip[k]=ip[k-1];
      nip[WN] += ip[WN];
      for (int k=0;k<=WN;k++) ip[k]=nip[k];
      for (int k=0;k<=WN;k++) iptr[(t+1)*16+k]=ip[k];
      avail[t+1] = 1.f - ip[WN];
    }
  }

  #pragma unroll
  for (int jj=0;jj<2;jj++){ int j=tid+jj*1024; sp[j]=sp0g[j]; D[j]=1.f; }
  __syncthreads();

  if (d==0){
    #pragma unroll
    for (int jj=0;jj<2;jj++){ int j=tid+jj*1024; q[j]=(j<HH-1)? sp[j+1]:0.f; }
    float ls=0.f;
    #pragma unroll
    for (int jj=0;jj<2;jj++) ls += q[tid+jj*1024];
    float s = blockReduceSum(ls, red);
    float sc = (s>0.f)? 1.f/s : 1.f;
    #pragma unroll
    for (int jj=0;jj<2;jj++){
      int j=tid+jj*1024;
      float qq=q[j];
      Wrow[j] = qq*sc;
      D[j] = 1.f - qq;
      sp[j] = qq + ((j==0)? sp[0] : 0.f);
    }
    __syncthreads();
    #pragma unroll
    for (int jj=0;jj<2;jj++){ int j=tid+jj*1024; q[j]=(j<HH-1)? sp[j+1]:0.f; }
    ls=0.f;
    #pragma unroll
    for (int jj=0;jj<2;jj++) ls += q[tid+jj*1024];
    s = blockReduceSum(ls, red);
    sc = (s>0.f)? 1.f/s : 1.f;
    #pragma unroll
    for (int jj=0;jj<2;jj++){
      int j=tid+jj*1024;
      float qq=q[j];
      Wrow[HH+j] = qq*sc*D[j];
      D[j] *= (1.f-qq);
      sp[j] = qq + ((j==0)? sp[0] : 0.f);
    }
    __syncthreads();
    #pragma unroll
    for (int jj=0;jj<2;jj++){
      int j=tid+jj*1024;
      float p=sp[j];
      Dfin[j] = D[j]*(1.f-p);
      cnew[j] = p;
      sptr[j] = (j==0)? 0.f : sp[j-1];
    }
  } else {
    const int nterms = d-1;
    for (int t=0;t<nterms;t++){
      #pragma unroll
      for (int jj=0;jj<2;jj++){
        int j=tid+jj*1024;
        float p=sp[j], f=1.f-p;
        D[j]*=f;
        for (int u=0;u<t;u++) c[u][j]*=f;
        c[t][j]=p;
      }
      __syncthreads();
      float sv[2];
      #pragma unroll
      for (int jj=0;jj<2;jj++){ int j=tid+jj*1024; sv[jj]=(j==0)?0.f:sp[j-1]; }
      __syncthreads();
      #pragma unroll
      for (int jj=0;jj<2;jj++){ int j=tid+jj*1024; sp[j]=sv[jj]; }
      __syncthreads();
    }
    #pragma unroll
    for (int jj=0;jj<2;jj++){ int j=tid+jj*1024; q[j]=(j<HH-1)? sp[j+1]:0.f; }
    float ls=0.f;
    #pragma unroll
    for (int jj=0;jj<2;jj++) ls += q[tid+jj*1024];
    float s = blockReduceSum(ls, red);
    float sc = (s>0.f)? 1.f/s : 1.f;
    for (int t=0;t<nterms;t++){
      float pc=0.f;
      #pragma unroll
      for (int jj=0;jj<2;jj++){ int j=tid+jj*1024; pc += q[j]*sc*c[t][j]; }
      pc = blockReduceSum(pc, red);
      if (tid==0) popc[d*4+t]=pc;
    }
    #pragma unroll
    for (int jj=0;jj<2;jj++){
      int j=tid+jj*1024;
      float qq=q[j];
      Wrow[(1+d)*HH+j] = qq*sc*D[j];
      float f = 1.f-qq;
      D[j] *= f;
      for (int t=0;t<nterms;t++) c[t][j] *= f;
      sp[j] = qq + ((j==0)? sp[0] : 0.f);
    }
    __syncthreads();
    #pragma unroll
    for (int jj=0;jj<2;jj++){
      int j=tid+jj*1024;
      float p=sp[j], f=1.f-p;
      Dfin[d*HH+j] = D[j]*f;
      for (int t=0;t<nterms;t++) cfin[(d*4+t)*HH+j] = c[t][j]*f;
      cnew[d*HH+j] = p;
      sptr[d*HH+j] = (j==0)? 0.f : sp[j-1];
    }
  }
}

// ---------------------------------------------------------------------------
// K2: rowsum partials, atomic-free: Rp[y][k][col]
// ---------------------------------------------------------------------------
__global__ __launch_bounds__(256) void k_rowsum(
    const float* __restrict__ stk, const float* __restrict__ wrow,
    float* __restrict__ Rp)
{
  __shared__ float wsh[7][64];
  const int col = blockIdx.x*256 + threadIdx.x;
  const int by  = blockIdx.y;
  const int r0  = by*64;
  for (int idx=threadIdx.x; idx<7*64; idx+=256){
    int k=idx>>6, r=idx&63;
    wsh[k][r]=wrow[k*HH + r0 + r];
  }
  __syncthreads();
  float a0=0,a1=0,a2=0,a3=0,a4=0,a5=0,a6=0;
  const float* sp = stk + (size_t)r0*ISZ + col;
  #pragma unroll 4
  for (int r=0;r<64;r++){
    float v = sp[(size_t)r*ISZ];
    a0+=wsh[0][r]*v; a1+=wsh[1][r]*v; a2+=wsh[2][r]*v; a3+=wsh[3][r]*v;
    a4+=wsh[4][r]*v; a5+=wsh[5][r]*v; a6+=wsh[6][r]*v;
  }
  Rp[(size_t)(by*7+0)*ISZ+col]=a0; Rp[(size_t)(by*7+1)*ISZ+col]=a1;
  Rp[(size_t)(by*7+2)*ISZ+col]=a2; Rp[(size_t)(by*7+3)*ISZ+col]=a3;
  Rp[(size_t)(by*7+4)*ISZ+col]=a4; Rp[(size_t)(by*7+5)*ISZ+col]=a5;
  Rp[(size_t)(by*7+6)*ISZ+col]=a6;
}

// ---------------------------------------------------------------------------
// K3: fused g-vectors + R reduction + Ivec/Hvec assembly
// ---------------------------------------------------------------------------
__global__ __launch_bounds__(128) void k_hv(
    const float* __restrict__ input, float* __restrict__ ws)
{
  __shared__ float gwS[80], pcS[24];
  const int tid=threadIdx.x;
  const int cx = blockIdx.x*128 + tid;
  if (tid<80) gwS[tid]=ws[O_GETW+tid];
  if (tid<24) pcS[tid]=ws[O_POPC+tid];
  __syncthreads();
  float inp[WN];
  #pragma unroll
  for (int k=0;k<WN;k++) inp[k]=input[k*ISZ+cx];
  float g[5];
  #pragma unroll
  for (int t=0;t<5;t++){
    float a=0.f;
    #pragma unroll
    for (int k=0;k<WN;k++) a += gwS[t*16+k]*inp[k];
    g[t]=a;
    ws[O_G + t*ISZ + cx]=a;
  }
  float R[7];
  #pragma unroll
  for (int k=0;k<7;k++){
    float a=0.f;
    for (int y=0;y<32;y++) a += ws[O_RPART + (size_t)(y*7+k)*ISZ + cx];
    R[k]=a;
  }
  ws[O_IVEC + cx]=R[0];
  ws[O_HVEC + cx]=R[1];
  #pragma unroll
  for (int d=1;d<ND;d++){
    ws[O_IVEC + d*ISZ + cx] = g[d-1];
    float h = R[1+d];
    for (int t=0;t<=d-2;t++) h += pcS[d*4+t]*g[t];
    ws[O_HVEC + d*ISZ + cx] = h;
  }
}

// ---------------------------------------------------------------------------
// Matvec, A/B software pipeline (R9 structure, best measured: 84 us) with
// NONTEMPORAL weight loads — weights are use-once streaming data; if the
// ~2.1 TB/s read wall is L2 pollution/thrash from 500 concurrent use-once
// streams, nt bypass recovers copy-class read BW (~3.1 TB/s, m13).
// X loads stay cached (they ARE the reused data).
// ---------------------------------------------------------------------------
__device__ __forceinline__ void mv_body2db(
    const float* __restrict__ W, int ldw,
    const float* __restrict__ Xg, const float* __restrict__ bias,
    float* __restrict__ Y, int bb)
{
  const int wv = threadIdx.x>>6, ln = threadIdx.x&63;
  const int row0 = bb*16 + wv*2;
  const float* wr0 = W + (size_t)row0*ldw;
  const float* wr1 = wr0 + ldw;
  const int k0 = ln*4;

  float a0[6]={0,0,0,0,0,0}, a1[6]={0,0,0,0,0,0};
  nf4 wA0, wA1, xA[6], wB0, wB1, xB[6];

  wA0 = ntload4(wr0 + k0);
  wA1 = ntload4(wr1 + k0);
  #pragma unroll
  for (int d=0;d<6;d++) xA[d] = *(const nf4*)(Xg + d*ISZ + k0);

  #pragma unroll 1
  for (int i=0;i<16;i+=2){
    const int k1 = k0 + (i+1)*256;
    wB0 = ntload4(wr0 + k1);
    wB1 = ntload4(wr1 + k1);
    #pragma unroll
    for (int d=0;d<6;d++) xB[d] = *(const nf4*)(Xg + d*ISZ + k1);
    #pragma unroll
    for (int d=0;d<6;d++){
      a0[d] += wA0.x*xA[d].x + wA0.y*xA[d].y + wA0.z*xA[d].z + wA0.w*xA[d].w;
      a1[d] += wA1.x*xA[d].x + wA1.y*xA[d].y + wA1.z*xA[d].z + wA1.w*xA[d].w;
    }
    if (i+2<16){
      const int k2 = k0 + (i+2)*256;
      wA0 = ntload4(wr0 + k2);
      wA1 = ntload4(wr1 + k2);
      #pragma unroll
      for (int d=0;d<6;d++) xA[d] = *(const nf4*)(Xg + d*ISZ + k2);
    }
    #pragma unroll
    for (int d=0;d<6;d++){
      a0[d] += wB0.x*xB[d].x + wB0.y*xB[d].y + wB0.z*xB[d].z + wB0.w*xB[d].w;
      a1[d] += wB1.x*xB[d].x + wB1.y*xB[d].y + wB1.z*xB[d].z + wB1.w*xB[d].w;
    }
  }

  #pragma unroll
  for (int d=0;d<6;d++){
    float v0=a0[d], v1=a1[d];
    #pragma unroll
    for (int o=32;o>0;o>>=1){ v0+=__shfl_down(v0,o); v1+=__shfl_down(v1,o); }
    if (ln==0){
      Y[d*ISZ+row0]   = v0 + (bias? bias[row0]   : 0.f);
      Y[d*ISZ+row0+1] = v1 + (bias? bias[row0+1] : 0.f);
    }
  }
}

// kin-half1(IVEC)->Z1 | ff(HVEC)->YFF | kin-half2(HVEC)->Z2 — one launch
__global__ __launch_bounds__(512) void k_matvecA(
    const float* __restrict__ ff_w, const float* __restrict__ ff_b,
    const float* __restrict__ kin_w, const float* __restrict__ kin_b,
    float* __restrict__ ws)
{
  const int task = blockIdx.x >> 8, bb = blockIdx.x & 255;
  if (task==0)      mv_body2db(kin_w,     2*ISZ, ws+O_IVEC, kin_b,   ws+O_Z1,  bb);
  else if (task==1) mv_body2db(ff_w,      ISZ,   ws+O_HVEC, ff_b,    ws+O_YFF, bb);
  else              mv_body2db(kin_w+ISZ, 2*ISZ, ws+O_HVEC, nullptr, ws+O_Z2,  bb);
}

// kouth(NEWINP)->YH | kouti(NEWINP)->YI — one launch
__global__ __launch_bounds__(512) void k_matvecB(
    const float* __restrict__ kouth_w, const float* __restrict__ kouth_b,
    const float* __restrict__ kouti_w, const float* __restrict__ kouti_b,
    float* __restrict__ ws)
{
  const int task = blockIdx.x >> 8, bb = blockIdx.x & 255;
  if (task==0) mv_body2db(kouth_w, ISZ, ws+O_NEWINP, kouth_b, ws+O_YH, bb);
  else         mv_body2db(kouti_w, ISZ, ws+O_NEWINP, kouti_b, ws+O_YI, bb);
}

// ---------------------------------------------------------------------------
// S1: perp_pred KLD, softmax(z)->new_inp, gate   (6 blocks)
// ---------------------------------------------------------------------------
__global__ __launch_bounds__(1024) void k_s1(
    const float* __restrict__ gate_w, const float* __restrict__ gate_b,
    float* __restrict__ ws)
{
  __shared__ float sm[96];
  const int d=blockIdx.x, tid=threadIdx.x;
  const float* y  = ws+O_YFF + d*ISZ;
  const float* z1 = ws+O_Z1  + d*ISZ;
  const float* z2 = ws+O_Z2  + d*ISZ;
  const float* iv = ws+O_IVEC+ d*ISZ;
  const float* hv = ws+O_HVEC+ d*ISZ;

  float yv[4], zv[4], ivv[4], hvv[4];
  #pragma unroll
  for (int i=0;i<4;i++){
    int cx=tid+i*1024;
    yv[i]=y[cx]; zv[i]=z1[cx]+z2[cx]; ivv[i]=iv[cx]; hvv[i]=hv[cx];
  }
  float mx[2]={-FLT_MAX,-FLT_MAX};
  #pragma unroll
  for (int i=0;i<4;i++){ mx[0]=fmaxf(mx[0],yv[i]); mx[1]=fmaxf(mx[1],zv[i]); }
  bRedMaxN<2>(mx,sm);

  float s5[5]={0,0,0,0,0};
  #pragma unroll
  for (int i=0;i<4;i++){
    s5[0]+=expf(yv[i]-mx[0]); s5[1]+=expf(zv[i]-mx[1]);
    s5[2]+=yv[i]; s5[3]+=ivv[i]; s5[4]+=hvv[i];
  }
  bRedSumN<5>(s5,sm);
  const float lse = mx[0]+logf(s5[0]);
  const float sP  = s5[2] - (float)ISZ*lse + (float)ISZ*EPSF;
  const float sQ  = s5[3] + (float)ISZ*EPSF;
  const float inv2= 1.f/s5[1];

  float kk[1]={0.f};
  #pragma unroll
  for (int i=0;i<4;i++){
    int cx=tid+i*1024;
    ws[O_NEWINP + d*ISZ + cx] = expf(zv[i]-mx[1])*inv2;
    float ph=((yv[i]-lse)+EPSF)/sP;
    float qh=(ivv[i]+EPSF)/sQ;
    kk[0]+=ph*(logf(ph)-logf(qh));
  }
  bRedSumN<1>(kk,sm);

  if (tid==0){
    float pp=kk[0];
    float a0=gate_w[0]*pp+gate_b[0];
    float a1=gate_w[1]*pp+gate_b[1];
    float mg=fmaxf(a0,a1);
    float e0=expf(a0-mg), e1=expf(a1-mg);
    float g1=e1/(e0+e1);
    if (s5[4]==0.f) g1=0.f;
    else if (s5[3]==0.f) g1=1.f;
    ws[O_SCAL+d]=pp; ws[O_SCAL+6+d]=g1;
    ws[O_SCAL+24+d]=sQ;
    ws[O_SCAL+30+d]=s5[4]+(float)ISZ*EPSF;
  }
}

// ---------------------------------------------------------------------------
// S2: both output KLDs, batched  (6 blocks)
// ---------------------------------------------------------------------------
__global__ __launch_bounds__(1024) void k_s2(float* __restrict__ ws)
{
  __shared__ float sm[96];
  const int d=blockIdx.x, tid=threadIdx.x;
  const float* yh = ws+O_YH  + d*ISZ;
  const float* yi = ws+O_YI  + d*ISZ;
  const float* hv = ws+O_HVEC+ d*ISZ;
  const float* iv = ws+O_IVEC+ d*ISZ;

  float yhv[4], yiv[4], hvv[4], ivv[4];
  #pragma unroll
  for (int i=0;i<4;i++){
    int cx=tid+i*1024;
    yhv[i]=yh[cx]; yiv[i]=yi[cx]; hvv[i]=hv[cx]; ivv[i]=iv[cx];
  }
  float mx[2]={-FLT_MAX,-FLT_MAX};
  #pragma unroll
  for (int i=0;i<4;i++){ mx[0]=fmaxf(mx[0],yhv[i]); mx[1]=fmaxf(mx[1],yiv[i]); }
  bRedMaxN<2>(mx,sm);
  float se[2]={0,0};
  #pragma unroll
  for (int i=0;i<4;i++){ se[0]+=expf(yhv[i]-mx[0]); se[1]+=expf(yiv[i]-mx[1]); }
  bRedSumN<2>(se,sm);
  const float invh=1.f/se[0], invi=1.f/se[1];
  const float spc = 1.f + (float)ISZ*EPSF;
  const float sqh = ws[O_SCAL+30+d], sqi = ws[O_SCAL+24+d];

  float kk[2]={0,0};
  #pragma unroll
  for (int i=0;i<4;i++){
    float ph=(expf(yhv[i]-mx[0])*invh+EPSF)/spc;
    float qh=(hvv[i]+EPSF)/sqh;
    kk[0]+=ph*(logf(ph)-logf(qh));
    float pi=(expf(yiv[i]-mx[1])*invi+EPSF)/spc;
    float qi=(ivv[i]+EPSF)/sqi;
    kk[1]+=pi*(logf(pi)-logf(qi));
  }
  bRedSumN<2>(kk,sm);
  if (tid==0) ws[O_SCAL+12+d] = ws[O_SCAL+d] + 0.5f*(kk[0]+kk[1]);
}

// ---------------------------------------------------------------------------
// STACK_OUT + FIN fused: out = Mw[j]*stack + sum_v Ceff[j][v]*V[v];
// block (0,0) additionally writes resperp, new_sp, new_ip (k_fin's job).
// ---------------------------------------------------------------------------
__global__ __launch_bounds__(256) void k_stack_out(
    const float* __restrict__ stk, const float* __restrict__ ws,
    float* __restrict__ out)
{
  __shared__ float Vt[10*1024];
  __shared__ float wsh[ND];
  __shared__ float mwS[8];
  __shared__ float ceS[8][10];
  __shared__ float finsm[8];
  const int tid=threadIdx.x;
  const int c0 = blockIdx.x*1024;
  const int j0 = blockIdx.y*8;

  if (tid==0){
    const float* g1=ws+O_SCAL+6; const float* av=ws+O_AVAIL;
    float wl[ND]; wl[0]=g1[0];
    for (int i=1;i<ND;i++) wl[i]=(1.f-wl[i-1])*g1[i]*av[i];
    float s=0.f; for (int i=0;i<ND;i++) s+=wl[i];
    for (int i=0;i<ND;i++) wsh[i]=wl[i]/s;
  }
  const float* V = ws+O_NEWINP;
  for (int idx=tid; idx<10*1024; idx+=256){
    int v=idx>>10, cc=idx&1023;
    Vt[idx] = V[v*ISZ + c0 + cc];
  }
  __syncthreads();
  if (tid<8){
    int j=j0+tid;
    float mw=0.f, ce[10]={0,0,0,0,0,0,0,0,0,0};
    for (int dd=0;dd<ND;dd++){
      float wd=wsh[dd];
      mw    += wd*ws[O_DFIN+dd*HH+j];
      ce[dd] = wd*ws[O_CNEW+dd*HH+j];
    }
    for (int t=0;t<4;t++){
      float a=0.f;
      for (int dd=t+2;dd<ND;dd++) a += wsh[dd]*ws[O_CFIN+(dd*4+t)*HH+j];
      ce[6+t]=a;
    }
    mwS[tid]=mw;
    for (int v=0;v<10;v++) ceS[tid][v]=ce[v];
  }
  __syncthreads();
  const int tx4 = tid*4;
  for (int r=0;r<8;r++){
    int j=j0+r;
    float mw = mwS[r];
    float4 sv = *(const float4*)(stk + (size_t)j*ISZ + c0 + tx4);
    float o0 = mw*sv.x, o1 = mw*sv.y, o2 = mw*sv.z, o3 = mw*sv.w;
    #pragma unroll
    for (int v=0;v<10;v++){
      const float* vr = Vt + v*1024 + tx4;
      float cv=ceS[r][v];
      o0 += cv*vr[0]; o1 += cv*vr[1]; o2 += cv*vr[2]; o3 += cv*vr[3];
    }
    float* op = out + 1 + (size_t)j*ISZ + c0 + tx4;
    op[0]=o0; op[1]=o1; op[2]=o2; op[3]=o3;
  }

  // ---- FIN duties on block (0,0) ----
  if (blockIdx.x==0 && blockIdx.y==0){
    const float* sptr = ws+O_SPTR;
    float snl[8]; float ms=0.f;
    #pragma unroll
    for (int jj=0;jj<8;jj++){
      int j = tid + jj*256;
      float sn=0.f;
      #pragma unroll
      for (int dd=0;dd<ND;dd++) sn += wsh[dd]*sptr[dd*HH+j];
      snl[jj]=sn; ms+=sn;
    }
    // reduce ms over 4 waves
    #pragma unroll
    for (int o=32;o>0;o>>=1) ms += __shfl_down(ms,o);
    if ((tid&63)==0) finsm[tid>>6]=ms;
    __syncthreads();
    float ssum = finsm[0]+finsm[1]+finsm[2]+finsm[3];
    #pragma unroll
    for (int jj=0;jj<8;jj++){
      int j = tid + jj*256;
      out[1 + (size_t)HH*ISZ + j] = (ssum>0.f)? snl[jj]/ssum : snl[jj];
    }
    if (tid==0){
      float rp=0.f;
      for (int dd=0;dd<ND;dd++) rp += wsh[dd]*ws[O_SCAL+12+dd];
      out[0]=rp;
      const float* iptr=ws+O_IPTR;
      float ipn[WN+1]; float is=0.f;
      for (int k=0;k<=WN;k++){
        float a=0.f;
        for (int dd=0;dd<ND;dd++) a += wsh[dd]*iptr[dd*16+k];
        ipn[k]=a; is+=a;
      }
      size_t base = 1 + (size_t)HH*ISZ + HH;
      for (int k=0;k<=WN;k++) out[base+k] = (is>0.f)? ipn[k]/is : ipn[k];
    }
  }
}

extern "C" void kernel_launch(void* const* d_in, const int* in_sizes, int n_in,
                              void* d_out, int out_size, void* d_ws, size_t ws_size,
                              hipStream_t stream)
{
  (void)in_sizes; (void)n_in; (void)out_size; (void)ws_size;
  const float* input   = (const float*)d_in[0];
  const float* stack   = (const float*)d_in[1];
  const float* sp0     = (const float*)d_in[2];
  const float* ip0     = (const float*)d_in[3];
  const float* ff_w    = (const float*)d_in[4];
  const float* ff_b    = (const float*)d_in[5];
  const float* gate_w  = (const float*)d_in[6];
  const float* gate_b  = (const float*)d_in[7];
  const float* kin_w   = (const float*)d_in[8];
  const float* kin_b   = (const float*)d_in[9];
  const float* kouth_w = (const float*)d_in[10];
  const float* kouth_b = (const float*)d_in[11];
  const float* kouti_w = (const float*)d_in[12];
  const float* kouti_b = (const float*)d_in[13];
  float* out = (float*)d_out;
  float* ws  = (float*)d_ws;

  k_ptr_prep<<<ND,1024,0,stream>>>(sp0, ip0, ws);
  k_rowsum<<<dim3(16,32),256,0,stream>>>(stack, ws+O_WROW, ws+O_RPART);
  k_hv<<<32,128,0,stream>>>(input, ws);
  k_matvecA<<<768,512,0,stream>>>(ff_w, ff_b, kin_w, kin_b, ws);
  k_s1<<<ND,1024,0,stream>>>(gate_w, gate_b, ws);
  k_matvecB<<<512,512,0,stream>>>(kouth_w, kouth_b, kouti_w, kouti_b, ws);
  k_s2<<<ND,1024,0,stream>>>(ws);
  k_stack_out<<<dim3(4,256),256,0,stream>>>(stack, ws, out);
}